// Round 5
// baseline (374.630 us; speedup 1.0000x reference)
//
#include <hip/hip_runtime.h>
#include <hip/hip_bf16.h>
#include <cstdint>
#include <cstddef>

#define TOK   8192
#define DIN   4096
#define DOUT  4096
#define RANK  16
#define KE    4160   // DIN + 16 (loraB) + 1 (bias) + 47 pad -> 65 * 64
#define NKT64 (KE / 64)

#define BM 256
#define BN 256

typedef __attribute__((ext_vector_type(8))) short bf16x8;
typedef __attribute__((ext_vector_type(4))) float f32x4;
typedef __attribute__((ext_vector_type(8))) unsigned short u16x8;

__device__ __constant__ float NF4_CODE_D[16] = {
    -1.0f, -0.6961928009986877f, -0.5250730514526367f, -0.39491748809814453f,
    -0.28444138169288635f, -0.18477343022823334f, -0.09105003625154495f, 0.0f,
    0.07958029955625534f, 0.16093020141124725f, 0.24611230194568634f,
    0.33791524171829224f, 0.44070982933044434f, 0.5626170039176941f,
    0.7229568362236023f, 1.0f};

__device__ __forceinline__ unsigned short f2bf(float f) {
    union { float f; unsigned u; } v; v.f = f;
    unsigned u = v.u;
    unsigned r = (u + 0x7FFFu + ((u >> 16) & 1u)) >> 16;  // round-nearest-even
    return (unsigned short)r;
}

__device__ __forceinline__ void async_copy16(const void* g, void* l) {
    __builtin_amdgcn_global_load_lds(
        (const __attribute__((address_space(1))) void*)g,
        (__attribute__((address_space(3))) void*)l,
        16, 0, 0);
}

// ---------------------------------------------------------------------------
// Kernel 1: x -> bf16 into [TOK][KE]; cols [4096,4112) = 4*(x@lora_A);
// col 4112 = 1.0 (bias col); [4113,4160) = 0.
// ---------------------------------------------------------------------------
__global__ __launch_bounds__(256) void prep_x(const float* __restrict__ x,
                                              const float* __restrict__ lora_A,
                                              unsigned short* __restrict__ xe) {
    const int tid = threadIdx.x;
    const int l = tid & 63;
    const int w = tid >> 6;
    const int t0 = blockIdx.x * 16 + w * 4;

    float p[4][16];
#pragma unroll
    for (int a = 0; a < 4; ++a)
#pragma unroll
        for (int r = 0; r < 16; ++r) p[a][r] = 0.f;

    for (int it = 0; it < 16; ++it) {
        const int kb = it * 256 + l * 4;
        float4 xv[4];
#pragma unroll
        for (int a = 0; a < 4; ++a)
            xv[a] = *(const float4*)(x + (size_t)(t0 + a) * DIN + kb);
#pragma unroll
        for (int a = 0; a < 4; ++a) {
            ushort4 s;
            s.x = f2bf(xv[a].x); s.y = f2bf(xv[a].y);
            s.z = f2bf(xv[a].z); s.w = f2bf(xv[a].w);
            *(ushort4*)(xe + (size_t)(t0 + a) * KE + kb) = s;
        }
#pragma unroll
        for (int j = 0; j < 4; ++j) {
            const float4* ap = (const float4*)(lora_A + (size_t)(kb + j) * RANK);
            const float4 a0 = ap[0], a1 = ap[1], a2 = ap[2], a3 = ap[3];
            const float av[16] = {a0.x, a0.y, a0.z, a0.w, a1.x, a1.y, a1.z, a1.w,
                                  a2.x, a2.y, a2.z, a2.w, a3.x, a3.y, a3.z, a3.w};
#pragma unroll
            for (int a = 0; a < 4; ++a) {
                const float xs = (j == 0) ? xv[a].x : (j == 1) ? xv[a].y
                                : (j == 2) ? xv[a].z : xv[a].w;
#pragma unroll
                for (int r = 0; r < 16; ++r) p[a][r] += xs * av[r];
            }
        }
    }

#pragma unroll
    for (int a = 0; a < 4; ++a) {
#pragma unroll
        for (int r = 0; r < 16; ++r) {
            float v = p[a][r];
#pragma unroll
            for (int off = 32; off > 0; off >>= 1) v += __shfl_xor(v, off, 64);
            if (l == r)
                xe[(size_t)(t0 + a) * KE + DIN + r] = f2bf(4.0f * v);  // SCALING=4
        }
        if (l >= 16)  // cols 4112..4159: bias-one then zeros
            xe[(size_t)(t0 + a) * KE + DIN + l] =
                (l == 16) ? (unsigned short)0x3F80u : (unsigned short)0u;
    }
}

// ---------------------------------------------------------------------------
// Kernel 2: NF4 dequant W -> bf16 into [DOUT][KE], cols [0,4096).
// ---------------------------------------------------------------------------
__global__ __launch_bounds__(256) void dequant_w(const int* __restrict__ codes,
                                                 const float* __restrict__ absmax,
                                                 unsigned short* __restrict__ we) {
    __shared__ float tab[16];
    if (threadIdx.x < 16) tab[threadIdx.x] = NF4_CODE_D[threadIdx.x];
    __syncthreads();
    const size_t tid = (size_t)blockIdx.x * 256 + threadIdx.x;
    const size_t base = tid * 8;
    const int o = (int)(base >> 12);          // / DIN
    const int k = (int)(base & (DIN - 1));
    const float am = absmax[base >> 6];
    const int4 c0 = *(const int4*)(codes + base);
    const int4 c1 = *(const int4*)(codes + base + 4);
    u16x8 ov;
    ov[0] = f2bf(tab[c0.x] * am);
    ov[1] = f2bf(tab[c0.y] * am);
    ov[2] = f2bf(tab[c0.z] * am);
    ov[3] = f2bf(tab[c0.w] * am);
    ov[4] = f2bf(tab[c1.x] * am);
    ov[5] = f2bf(tab[c1.y] * am);
    ov[6] = f2bf(tab[c1.z] * am);
    ov[7] = f2bf(tab[c1.w] * am);
    *(u16x8*)(we + (size_t)o * KE + k) = ov;
}

// ---------------------------------------------------------------------------
// Kernel 3: W extended tail: cols [4096,4112) = lora_B^T, 4112 = bias, rest 0.
// ---------------------------------------------------------------------------
__global__ __launch_bounds__(256) void fill_wtail(const float* __restrict__ lora_B,
                                                  const float* __restrict__ bias,
                                                  unsigned short* __restrict__ we) {
    const int o = blockIdx.x * 256 + threadIdx.x;
    if (o >= DOUT) return;
    unsigned short* dst = we + (size_t)o * KE + DIN;
#pragma unroll
    for (int r = 0; r < RANK; ++r) dst[r] = f2bf(lora_B[(size_t)r * DOUT + o]);
    dst[16] = f2bf(bias[o]);
#pragma unroll
    for (int r = 17; r < 64; ++r) dst[r] = 0;
}

// ---------------------------------------------------------------------------
// Kernel 4: C[t,o] = sum_k A[t,k]*B[o,k]  (K-major bf16, K=KE)
// R5: m201-style phase skeleton at slice (K32) granularity. 4 phases per
// K64-tile; each phase = {ds_reads for THIS phase | stage 1 slice-half |
// [vmcnt(4) at publish phases] -> s_barrier -> lgkmcnt(0)+sched_barrier ->
// setprio(1) -> 16 MFMA -> setprio(0) -> s_barrier}.
//
// Publication is ONE PHASE EARLY so no phase reads a slice published at its
// own barrier: ph1 publishes S1(t), ph3 publishes S0(t+1) (prologue
// publishes S0(0)).
// vmcnt ledger (per wave, 2 loads per stage; stages issue BEFORE the wait):
//   invariant entering ph0(t): outstanding = {A(t,1),B(t,1)} = 4
//   ph1: +A(t+1,0)@ph0 +B(t+1,0)@ph1 = 8 -> vmcnt(4) retires A(t,1),B(t,1)
//        = S1(t) published
//   ph3: +A(t+1,1)@ph2 +B(t+1,1)@ph3 = 8 -> vmcnt(4) retires
//        A(t+1,0),B(t+1,0) = S0(t+1) published; leaves {A(t+1,1),B(t+1,1)}=4
//        -> invariant holds for t+1.  Last tile: vmcnt(0).
// WAR on slot reuse (4 slots, reuse distance 4 phases, readers' lgkm drains
// precede >=2 intervening barriers before the overwriting stage).
// ---------------------------------------------------------------------------
__global__ __launch_bounds__(512, 2) void gemm_bt(const unsigned short* __restrict__ A,
                                                  const unsigned short* __restrict__ B,
                                                  float* __restrict__ C) {
    __shared__ __attribute__((aligned(1024))) char smem[4 * 32768];  // 128 KiB

    const int tid = threadIdx.x;
    const int l = tid & 63;
    const int w = tid >> 6;
    const int wm = w >> 2;      // 0..1
    const int wn = w & 3;       // 0..3

    const int tm = blockIdx.x >> 4;     // 32 row tiles
    const int tn = blockIdx.x & 15;     // 16 col tiles
    const int rowBase = tm * BM;
    const int colBase = tn * BN;

    // staging coords (pre-swizzled global source; linear LDS dest)
    int srow[2], scolb[2], loffs[2];
#pragma unroll
    for (int g = 0; g < 2; ++g) {
        const int loff = g * 8192 + tid * 16;               // linear LDS byte
        const int soff = loff ^ (((loff >> 7) & 7) << 4);   // involution
        loffs[g] = loff;
        srow[g] = soff >> 6;          // row of [256][32] bf16 slice
        scolb[g] = soff & 63;         // byte within 64B row
    }

    auto stageA = [&](int tt, int kh, int slot) {
        char* dst = smem + slot * 32768;
        const int k0 = tt * 64 + kh * 32;
#pragma unroll
        for (int g = 0; g < 2; ++g)
            async_copy16((const char*)A + ((size_t)(rowBase + srow[g]) * KE + k0) * 2 + scolb[g],
                         dst + loffs[g]);
    };
    auto stageB = [&](int tt, int kh, int slot) {
        char* dst = smem + slot * 32768 + 16384;
        const int k0 = tt * 64 + kh * 32;
#pragma unroll
        for (int g = 0; g < 2; ++g)
            async_copy16((const char*)B + ((size_t)(colBase + srow[g]) * KE + k0) * 2 + scolb[g],
                         dst + loffs[g]);
    };

    // swizzled fragment read offsets (within a 16 KiB slice)
    const int lmask = ((l >> 1) & 7) << 4;
    const int aoff = (((wm * 128 + (l & 15)) * 64) + ((l >> 4) * 16)) ^ lmask;
    const int boff = (((wn * 64 + (l & 15)) * 64) + ((l >> 4) * 16)) ^ lmask;

    f32x4 acc[8][4];
#pragma unroll
    for (int m = 0; m < 8; ++m)
#pragma unroll
        for (int n = 0; n < 4; ++n) acc[m][n] = (f32x4){0.f, 0.f, 0.f, 0.f};

    // prologue: tile 0 slices into slots 0,1; publish S0(0)
    stageA(0, 0, 0); stageB(0, 0, 0);
    stageA(0, 1, 1); stageB(0, 1, 1);
    asm volatile("s_waitcnt vmcnt(4)" ::: "memory");
    __builtin_amdgcn_s_barrier();
    __builtin_amdgcn_sched_barrier(0);

    for (int t = 0; t < NKT64; ++t) {
        const char* S0 = smem + ((2 * t) & 3) * 32768;       // slice (t,k0)
        const char* S1 = smem + ((2 * t + 1) & 3) * 32768;   // slice (t,k1)
        const int d0 = (2 * t + 2) & 3, d1 = (2 * t + 3) & 3;
        const bool more = (t + 1 < NKT64);

        bf16x8 bf[4], af[4];

        // ---- phase 0: reads b0+aLo (S0); stage A(t+1,0); MFMA acc[0..3] k0
#pragma unroll
        for (int n = 0; n < 4; ++n)
            bf[n] = *(const bf16x8*)(S0 + 16384 + boff + n * 1024);
#pragma unroll
        for (int m = 0; m < 4; ++m)
            af[m] = *(const bf16x8*)(S0 + aoff + m * 1024);
        if (more) stageA(t + 1, 0, d0);
        __builtin_amdgcn_s_barrier();
        asm volatile("s_waitcnt lgkmcnt(0)" ::: "memory");
        __builtin_amdgcn_sched_barrier(0);
        __builtin_amdgcn_s_setprio(1);
#pragma unroll
        for (int m = 0; m < 4; ++m)
#pragma unroll
            for (int n = 0; n < 4; ++n)
                acc[m][n] = __builtin_amdgcn_mfma_f32_16x16x32_bf16(
                    af[m], bf[n], acc[m][n], 0, 0, 0);
        __builtin_amdgcn_s_setprio(0);
        __builtin_amdgcn_s_barrier();
        __builtin_amdgcn_sched_barrier(0);

        // ---- phase 1: reads aHi (S0); stage B(t+1,0); vmcnt(4) publishes
        //      S1(t); MFMA acc[4..7] k0
#pragma unroll
        for (int m = 0; m < 4; ++m)
            af[m] = *(const bf16x8*)(S0 + aoff + (4 + m) * 1024);
        if (more) stageB(t + 1, 0, d0);
        if (more) {
            asm volatile("s_waitcnt vmcnt(4)" ::: "memory");
        } else {
            asm volatile("s_waitcnt vmcnt(0)" ::: "memory");
        }
        __builtin_amdgcn_s_barrier();
        asm volatile("s_waitcnt lgkmcnt(0)" ::: "memory");
        __builtin_amdgcn_sched_barrier(0);
        __builtin_amdgcn_s_setprio(1);
#pragma unroll
        for (int m = 0; m < 4; ++m)
#pragma unroll
            for (int n = 0; n < 4; ++n)
                acc[4 + m][n] = __builtin_amdgcn_mfma_f32_16x16x32_bf16(
                    af[m], bf[n], acc[4 + m][n], 0, 0, 0);
        __builtin_amdgcn_s_setprio(0);
        __builtin_amdgcn_s_barrier();
        __builtin_amdgcn_sched_barrier(0);

        // ---- phase 2: reads b1+aLo (S1); stage A(t+1,1); MFMA acc[0..3] k1
#pragma unroll
        for (int n = 0; n < 4; ++n)
            bf[n] = *(const bf16x8*)(S1 + 16384 + boff + n * 1024);
#pragma unroll
        for (int m = 0; m < 4; ++m)
            af[m] = *(const bf16x8*)(S1 + aoff + m * 1024);
        if (more) stageA(t + 1, 1, d1);
        __builtin_amdgcn_s_barrier();
        asm volatile("s_waitcnt lgkmcnt(0)" ::: "memory");
        __builtin_amdgcn_sched_barrier(0);
        __builtin_amdgcn_s_setprio(1);
#pragma unroll
        for (int m = 0; m < 4; ++m)
#pragma unroll
            for (int n = 0; n < 4; ++n)
                acc[m][n] = __builtin_amdgcn_mfma_f32_16x16x32_bf16(
                    af[m], bf[n], acc[m][n], 0, 0, 0);
        __builtin_amdgcn_s_setprio(0);
        __builtin_amdgcn_s_barrier();
        __builtin_amdgcn_sched_barrier(0);

        // ---- phase 3: reads aHi (S1); stage B(t+1,1); vmcnt(4) publishes
        //      S0(t+1); MFMA acc[4..7] k1
#pragma unroll
        for (int m = 0; m < 4; ++m)
            af[m] = *(const bf16x8*)(S1 + aoff + (4 + m) * 1024);
        if (more) stageB(t + 1, 1, d1);
        if (more) {
            asm volatile("s_waitcnt vmcnt(4)" ::: "memory");
        } else {
            asm volatile("s_waitcnt vmcnt(0)" ::: "memory");
        }
        __builtin_amdgcn_s_barrier();
        asm volatile("s_waitcnt lgkmcnt(0)" ::: "memory");
        __builtin_amdgcn_sched_barrier(0);
        __builtin_amdgcn_s_setprio(1);
#pragma unroll
        for (int m = 0; m < 4; ++m)
#pragma unroll
            for (int n = 0; n < 4; ++n)
                acc[4 + m][n] = __builtin_amdgcn_mfma_f32_16x16x32_bf16(
                    af[m], bf[n], acc[4 + m][n], 0, 0, 0);
        __builtin_amdgcn_s_setprio(0);
        __builtin_amdgcn_s_barrier();
        __builtin_amdgcn_sched_barrier(0);
    }

    // epilogue: C/D map col = l&15, row = (l>>4)*4 + reg
#pragma unroll
    for (int m = 0; m < 8; ++m) {
        const int rowg = rowBase + wm * 128 + m * 16 + (l >> 4) * 4;
#pragma unroll
        for (int n = 0; n < 4; ++n) {
            const int colg = colBase + wn * 64 + n * 16 + (l & 15);
            float* cp = C + (size_t)rowg * DOUT + colg;
#pragma unroll
            for (int r = 0; r < 4; ++r) cp[(size_t)r * DOUT] = acc[m][n][r];
        }
    }
}

// ---------------------------------------------------------------------------
extern "C" void kernel_launch(void* const* d_in, const int* in_sizes, int n_in,
                              void* d_out, int out_size, void* d_ws, size_t ws_size,
                              hipStream_t stream) {
    const float* x      = (const float*)d_in[0];
    const int*   codes  = (const int*)d_in[1];
    const float* absmax = (const float*)d_in[2];
    const float* bias   = (const float*)d_in[3];
    const float* lora_A = (const float*)d_in[4];
    const float* lora_B = (const float*)d_in[5];
    float* out = (float*)d_out;

    unsigned short* xe = (unsigned short*)d_ws;        // [TOK][KE] bf16
    unsigned short* we = xe + (size_t)TOK * KE;        // [DOUT][KE] bf16

    prep_x<<<TOK / 16, 256, 0, stream>>>(x, lora_A, xe);
    dequant_w<<<(DOUT * (size_t)DIN / 8) / 256, 256, 0, stream>>>(codes, absmax, we);
    fill_wtail<<<DOUT / 256, 256, 0, stream>>>(lora_B, bias, we);
    gemm_bt<<<(TOK / BM) * (DOUT / BN), 512, 0, stream>>>(xe, we, out);
}

// Round 6
// 355.964 us; speedup vs baseline: 1.0524x; 1.0524x over previous
//
#include <hip/hip_runtime.h>
#include <hip/hip_bf16.h>
#include <cstdint>
#include <cstddef>

#define TOK   8192
#define DIN   4096
#define DOUT  4096
#define RANK  16
#define KE    4160   // DIN + 16 (loraB) + 1 (bias) + 47 pad -> 65 * 64
#define NKT64 (KE / 64)

#define BM 256
#define BN 256

// prep_fused block ranges
#define PXB 512                    // prep_x blocks
#define DQB 8192                   // dequant blocks
#define TLB 16                     // tail blocks

typedef __attribute__((ext_vector_type(8))) short bf16x8;
typedef __attribute__((ext_vector_type(4))) float f32x4;
typedef __attribute__((ext_vector_type(8))) unsigned short u16x8;

__device__ __constant__ float NF4_CODE_D[16] = {
    -1.0f, -0.6961928009986877f, -0.5250730514526367f, -0.39491748809814453f,
    -0.28444138169288635f, -0.18477343022823334f, -0.09105003625154495f, 0.0f,
    0.07958029955625534f, 0.16093020141124725f, 0.24611230194568634f,
    0.33791524171829224f, 0.44070982933044434f, 0.5626170039176941f,
    0.7229568362236023f, 1.0f};

__device__ __forceinline__ unsigned short f2bf(float f) {
    union { float f; unsigned u; } v; v.f = f;
    unsigned u = v.u;
    unsigned r = (u + 0x7FFFu + ((u >> 16) & 1u)) >> 16;  // round-nearest-even
    return (unsigned short)r;
}

__device__ __forceinline__ void async_copy16(const void* g, void* l) {
    __builtin_amdgcn_global_load_lds(
        (const __attribute__((address_space(1))) void*)g,
        (__attribute__((address_space(3))) void*)l,
        16, 0, 0);
}

// ---------------------------------------------------------------------------
// Fused prep: one launch, three block ranges.
//  [0, PXB):        x -> bf16 xe[TOK][KE]; cols [4096,4112)=4*(x@lora_A);
//                   col 4112 = 1.0; rest 0.
//  [PXB, PXB+DQB):  NF4 dequant -> we[DOUT][KE] cols [0,4096)
//  [PXB+DQB, +TLB): we tail cols: loraB^T, bias, zeros
// ---------------------------------------------------------------------------
__global__ __launch_bounds__(256) void prep_fused(
        const float* __restrict__ x, const float* __restrict__ lora_A,
        const int* __restrict__ codes, const float* __restrict__ absmax,
        const float* __restrict__ bias, const float* __restrict__ lora_B,
        unsigned short* __restrict__ xe, unsigned short* __restrict__ we) {
    __shared__ float tab[16];
    const int bid = blockIdx.x;
    const int tid = threadIdx.x;

    if (bid < PXB) {
        // ---- prep_x ----
        const int l = tid & 63;
        const int w = tid >> 6;
        const int t0 = bid * 16 + w * 4;

        float p[4][16];
#pragma unroll
        for (int a = 0; a < 4; ++a)
#pragma unroll
            for (int r = 0; r < 16; ++r) p[a][r] = 0.f;

        for (int it = 0; it < 16; ++it) {
            const int kb = it * 256 + l * 4;
            float4 xv[4];
#pragma unroll
            for (int a = 0; a < 4; ++a)
                xv[a] = *(const float4*)(x + (size_t)(t0 + a) * DIN + kb);
#pragma unroll
            for (int a = 0; a < 4; ++a) {
                ushort4 s;
                s.x = f2bf(xv[a].x); s.y = f2bf(xv[a].y);
                s.z = f2bf(xv[a].z); s.w = f2bf(xv[a].w);
                *(ushort4*)(xe + (size_t)(t0 + a) * KE + kb) = s;
            }
#pragma unroll
            for (int j = 0; j < 4; ++j) {
                const float4* ap = (const float4*)(lora_A + (size_t)(kb + j) * RANK);
                const float4 a0 = ap[0], a1 = ap[1], a2 = ap[2], a3 = ap[3];
                const float av[16] = {a0.x, a0.y, a0.z, a0.w, a1.x, a1.y, a1.z, a1.w,
                                      a2.x, a2.y, a2.z, a2.w, a3.x, a3.y, a3.z, a3.w};
#pragma unroll
                for (int a = 0; a < 4; ++a) {
                    const float xs = (j == 0) ? xv[a].x : (j == 1) ? xv[a].y
                                    : (j == 2) ? xv[a].z : xv[a].w;
#pragma unroll
                    for (int r = 0; r < 16; ++r) p[a][r] += xs * av[r];
                }
            }
        }

#pragma unroll
        for (int a = 0; a < 4; ++a) {
#pragma unroll
            for (int r = 0; r < 16; ++r) {
                float v = p[a][r];
#pragma unroll
                for (int off = 32; off > 0; off >>= 1) v += __shfl_xor(v, off, 64);
                if (l == r)
                    xe[(size_t)(t0 + a) * KE + DIN + r] = f2bf(4.0f * v);  // SCALING=4
            }
            if (l >= 16)  // cols 4112..4159: bias-one then zeros
                xe[(size_t)(t0 + a) * KE + DIN + l] =
                    (l == 16) ? (unsigned short)0x3F80u : (unsigned short)0u;
        }
    } else if (bid < PXB + DQB) {
        // ---- dequant_w ----
        if (tid < 16) tab[tid] = NF4_CODE_D[tid];
        __syncthreads();
        const size_t t = (size_t)(bid - PXB) * 256 + tid;
        const size_t base = t * 8;
        const int o = (int)(base >> 12);          // / DIN
        const int k = (int)(base & (DIN - 1));
        const float am = absmax[base >> 6];
        const int4 c0 = *(const int4*)(codes + base);
        const int4 c1 = *(const int4*)(codes + base + 4);
        u16x8 ov;
        ov[0] = f2bf(tab[c0.x] * am);
        ov[1] = f2bf(tab[c0.y] * am);
        ov[2] = f2bf(tab[c0.z] * am);
        ov[3] = f2bf(tab[c0.w] * am);
        ov[4] = f2bf(tab[c1.x] * am);
        ov[5] = f2bf(tab[c1.y] * am);
        ov[6] = f2bf(tab[c1.z] * am);
        ov[7] = f2bf(tab[c1.w] * am);
        *(u16x8*)(we + (size_t)o * KE + k) = ov;
    } else {
        // ---- fill we tail ----
        const int o = (bid - PXB - DQB) * 256 + tid;
        unsigned short* dst = we + (size_t)o * KE + DIN;
#pragma unroll
        for (int r = 0; r < RANK; ++r) dst[r] = f2bf(lora_B[(size_t)r * DOUT + o]);
        dst[16] = f2bf(bias[o]);
#pragma unroll
        for (int r = 17; r < 64; ++r) dst[r] = 0;
    }
}

// ---------------------------------------------------------------------------
// Kernel 2: C[t,o] = sum_k A[t,k]*B[o,k]  (K-major bf16, K=KE)
// R6 = R4 (one-phase-ahead ds_read pipelining, counted lgkm via compiler, 2
// barriers + 2 counted vmcnt per K64-tile) with DEEPER staging: both halves
// of a slice are issued in one phase, giving every slice a uniform
// stage->publish distance of 3 phases.
//   ph0: stage A(t+1,0)+B(t+1,0) -> slot d0
//   ph1: vmcnt(4) publishes S1(t)   [staged at ph2(t-1), 3 phases back]
//   ph2: stage A(t+1,1)+B(t+1,1) -> slot d1
//   ph3: vmcnt(4) publishes S0(t+1) [staged at ph0(t), 3 phases back]
// vmcnt ledger (per wave, 2 loads per stageA/stageB):
//   entering ph0(t): outstanding = {S1(t)} = 4
//   ph0 +4 -> 8; ph1 vmcnt(4) retires S1(t) -> 4
//   ph2 +4 -> 8; ph3 vmcnt(4) retires S0(t+1) -> 4 = {S1(t+1)}  (induction)
//   last tile: ph1 vmcnt(0); ph3 nothing staged, no wait needed.
// WAR: each overwriting stage is issued after a barrier that postdates all
// reads of the slot's previous slice (reads retire before their consuming
// MFMA cluster, which precedes that barrier for every wave).
// ---------------------------------------------------------------------------
__global__ __launch_bounds__(512, 2) void gemm_bt(const unsigned short* __restrict__ A,
                                                  const unsigned short* __restrict__ B,
                                                  float* __restrict__ C) {
    __shared__ __attribute__((aligned(1024))) char smem[4 * 32768];  // 128 KiB

    const int tid = threadIdx.x;
    const int l = tid & 63;
    const int w = tid >> 6;
    const int wm = w >> 2;      // 0..1
    const int wn = w & 3;       // 0..3

    const int tm = blockIdx.x >> 4;     // 32 row tiles
    const int tn = blockIdx.x & 15;     // 16 col tiles
    const int rowBase = tm * BM;
    const int colBase = tn * BN;

    // staging coords (pre-swizzled global source; linear LDS dest)
    int srow[2], scolb[2], loffs[2];
#pragma unroll
    for (int g = 0; g < 2; ++g) {
        const int loff = g * 8192 + tid * 16;               // linear LDS byte
        const int soff = loff ^ (((loff >> 7) & 7) << 4);   // involution
        loffs[g] = loff;
        srow[g] = soff >> 6;          // row of [256][32] bf16 slice
        scolb[g] = soff & 63;         // byte within 64B row
    }

    auto stageA = [&](int tt, int kh, int slot) {
        char* dst = smem + slot * 32768;
        const int k0 = tt * 64 + kh * 32;
#pragma unroll
        for (int g = 0; g < 2; ++g)
            async_copy16((const char*)A + ((size_t)(rowBase + srow[g]) * KE + k0) * 2 + scolb[g],
                         dst + loffs[g]);
    };
    auto stageB = [&](int tt, int kh, int slot) {
        char* dst = smem + slot * 32768 + 16384;
        const int k0 = tt * 64 + kh * 32;
#pragma unroll
        for (int g = 0; g < 2; ++g)
            async_copy16((const char*)B + ((size_t)(colBase + srow[g]) * KE + k0) * 2 + scolb[g],
                         dst + loffs[g]);
    };

    // swizzled fragment read offsets (within a 16 KiB slice)
    const int lmask = ((l >> 1) & 7) << 4;
    const int aoff = (((wm * 128 + (l & 15)) * 64) + ((l >> 4) * 16)) ^ lmask;
    const int boff = (((wn * 64 + (l & 15)) * 64) + ((l >> 4) * 16)) ^ lmask;

    f32x4 acc[8][4];
#pragma unroll
    for (int m = 0; m < 8; ++m)
#pragma unroll
        for (int n = 0; n < 4; ++n) acc[m][n] = (f32x4){0.f, 0.f, 0.f, 0.f};

    bf16x8 aLo[4], aHi[4], aLo2[4], aHi2[4], bCur[4], bNxt[4];

    // prologue: tile 0 slices into slots 0,1; publish S0(0); preload ph0 regs
    stageA(0, 0, 0); stageB(0, 0, 0);
    stageA(0, 1, 1); stageB(0, 1, 1);
    asm volatile("s_waitcnt vmcnt(4)" ::: "memory");
    __builtin_amdgcn_s_barrier();
    {
        const char* S0 = smem;  // slot 0
#pragma unroll
        for (int n = 0; n < 4; ++n)
            bCur[n] = *(const bf16x8*)(S0 + 16384 + boff + n * 1024);
#pragma unroll
        for (int m = 0; m < 4; ++m)
            aLo[m] = *(const bf16x8*)(S0 + aoff + m * 1024);
    }

    for (int t = 0; t < NKT64; ++t) {
        const char* S0 = smem + ((2 * t) & 3) * 32768;       // slice (t,k0)
        const char* S1 = smem + ((2 * t + 1) & 3) * 32768;   // slice (t,k1)
        const char* Sn = smem + ((2 * t + 2) & 3) * 32768;   // slice (t+1,k0)
        const int d0 = (2 * t + 2) & 3, d1 = (2 * t + 3) & 3;
        const bool more = (t + 1 < NKT64);

        // ---- phase 0: MFMA(aLo x bCur); read-ahead aHi(S0); stage S0(t+1)
#pragma unroll
        for (int m = 0; m < 4; ++m)
            aHi[m] = *(const bf16x8*)(S0 + aoff + (4 + m) * 1024);
        if (more) { stageA(t + 1, 0, d0); stageB(t + 1, 0, d0); }
        __builtin_amdgcn_sched_barrier(0);
        __builtin_amdgcn_s_setprio(1);
#pragma unroll
        for (int m = 0; m < 4; ++m)
#pragma unroll
            for (int n = 0; n < 4; ++n)
                acc[m][n] = __builtin_amdgcn_mfma_f32_16x16x32_bf16(
                    aLo[m], bCur[n], acc[m][n], 0, 0, 0);
        __builtin_amdgcn_s_setprio(0);
        __builtin_amdgcn_sched_barrier(0);

        // ---- phase 1: publish S1(t); MFMA(aHi x bCur); read bNxt,aLo2(S1) --
        if (more) {
            asm volatile("s_waitcnt vmcnt(4)" ::: "memory");
        } else {
            asm volatile("s_waitcnt vmcnt(0)" ::: "memory");
        }
        __builtin_amdgcn_s_barrier();
        __builtin_amdgcn_sched_barrier(0);
#pragma unroll
        for (int n = 0; n < 4; ++n)
            bNxt[n] = *(const bf16x8*)(S1 + 16384 + boff + n * 1024);
#pragma unroll
        for (int m = 0; m < 4; ++m)
            aLo2[m] = *(const bf16x8*)(S1 + aoff + m * 1024);
        __builtin_amdgcn_sched_barrier(0);
        __builtin_amdgcn_s_setprio(1);
#pragma unroll
        for (int m = 0; m < 4; ++m)
#pragma unroll
            for (int n = 0; n < 4; ++n)
                acc[4 + m][n] = __builtin_amdgcn_mfma_f32_16x16x32_bf16(
                    aHi[m], bCur[n], acc[4 + m][n], 0, 0, 0);
        __builtin_amdgcn_s_setprio(0);
        __builtin_amdgcn_sched_barrier(0);

        // ---- phase 2: MFMA(aLo2 x bNxt); read-ahead aHi2(S1); stage S1(t+1)
#pragma unroll
        for (int m = 0; m < 4; ++m)
            aHi2[m] = *(const bf16x8*)(S1 + aoff + (4 + m) * 1024);
        if (more) { stageA(t + 1, 1, d1); stageB(t + 1, 1, d1); }
        __builtin_amdgcn_sched_barrier(0);
        __builtin_amdgcn_s_setprio(1);
#pragma unroll
        for (int m = 0; m < 4; ++m)
#pragma unroll
            for (int n = 0; n < 4; ++n)
                acc[m][n] = __builtin_amdgcn_mfma_f32_16x16x32_bf16(
                    aLo2[m], bNxt[n], acc[m][n], 0, 0, 0);
        __builtin_amdgcn_s_setprio(0);
        __builtin_amdgcn_sched_barrier(0);

        // ---- phase 3: publish S0(t+1); MFMA(aHi2 x bNxt); read bCur,aLo ----
        if (more) {
            asm volatile("s_waitcnt vmcnt(4)" ::: "memory");
            __builtin_amdgcn_s_barrier();
            __builtin_amdgcn_sched_barrier(0);
#pragma unroll
            for (int n = 0; n < 4; ++n)
                bCur[n] = *(const bf16x8*)(Sn + 16384 + boff + n * 1024);
#pragma unroll
            for (int m = 0; m < 4; ++m)
                aLo[m] = *(const bf16x8*)(Sn + aoff + m * 1024);
        }
        __builtin_amdgcn_sched_barrier(0);
        __builtin_amdgcn_s_setprio(1);
#pragma unroll
        for (int m = 0; m < 4; ++m)
#pragma unroll
            for (int n = 0; n < 4; ++n)
                acc[4 + m][n] = __builtin_amdgcn_mfma_f32_16x16x32_bf16(
                    aHi2[m], bNxt[n], acc[4 + m][n], 0, 0, 0);
        __builtin_amdgcn_s_setprio(0);
        __builtin_amdgcn_sched_barrier(0);
    }

    // epilogue: C/D map col = l&15, row = (l>>4)*4 + reg
#pragma unroll
    for (int m = 0; m < 8; ++m) {
        const int rowg = rowBase + wm * 128 + m * 16 + (l >> 4) * 4;
#pragma unroll
        for (int n = 0; n < 4; ++n) {
            const int colg = colBase + wn * 64 + n * 16 + (l & 15);
            float* cp = C + (size_t)rowg * DOUT + colg;
#pragma unroll
            for (int r = 0; r < 4; ++r) cp[(size_t)r * DOUT] = acc[m][n][r];
        }
    }
}

// ---------------------------------------------------------------------------
extern "C" void kernel_launch(void* const* d_in, const int* in_sizes, int n_in,
                              void* d_out, int out_size, void* d_ws, size_t ws_size,
                              hipStream_t stream) {
    const float* x      = (const float*)d_in[0];
    const int*   codes  = (const int*)d_in[1];
    const float* absmax = (const float*)d_in[2];
    const float* bias   = (const float*)d_in[3];
    const float* lora_A = (const float*)d_in[4];
    const float* lora_B = (const float*)d_in[5];
    float* out = (float*)d_out;

    unsigned short* xe = (unsigned short*)d_ws;        // [TOK][KE] bf16
    unsigned short* we = xe + (size_t)TOK * KE;        // [DOUT][KE] bf16

    prep_fused<<<PXB + DQB + TLB, 256, 0, stream>>>(x, lora_A, codes, absmax,
                                                    bias, lora_B, xe, we);
    gemm_bt<<<(TOK / BM) * (DOUT / BN), 512, 0, stream>>>(xe, we, out);
}